// Round 12
// baseline (60.648 us; speedup 1.0000x reference)
//
#include <hip/hip_runtime.h>
#include <math.h>

#define T_TOTAL 8192
#define D_TOTAL 4096
#define E 64
#define TOPK 8
#define NKB (D_TOTAL / 32)      // 128 k-blocks of 32
#define NF  (NKB * 4 * 64)      // short8 elems per split array

#define S_SPLIT 8               // K-split across blockIdx.y
#define KCH (D_TOTAL / S_SPLIT) // 512 K per block
#define NPH (KCH / 32)          // 16 phases (1 kb each)

typedef short short8 __attribute__((ext_vector_type(8)));
typedef float f32x4 __attribute__((ext_vector_type(4)));

// scalar split (prep kernel)
__device__ __forceinline__ void split3(const float* v8, short8& h, short8& m, short8& l) {
#pragma unroll
    for (int j = 0; j < 8; ++j) {
        const float f = v8[j];
        const unsigned u = __float_as_uint(f);
        const unsigned hu = u & 0xffff0000u;
        const float r1 = f - __uint_as_float(hu);
        const unsigned mu = __float_as_uint(r1) & 0xffff0000u;
        const float r2 = r1 - __uint_as_float(mu);
        const unsigned lu = __float_as_uint(r2);
        h[j] = (short)(hu >> 16);
        m[j] = (short)(mu >> 16);
        l[j] = (short)(lu >> 16);
    }
}

// v_perm-based split: pack 2 bf16 per op
__device__ __forceinline__ void split3v(const float* v, short8& h, short8& m, short8& l) {
    unsigned* hp = reinterpret_cast<unsigned*>(&h);
    unsigned* mp = reinterpret_cast<unsigned*>(&m);
    unsigned* lp = reinterpret_cast<unsigned*>(&l);
#pragma unroll
    for (int p = 0; p < 4; ++p) {
        const float a = v[2 * p], b = v[2 * p + 1];
        const unsigned hw = __builtin_amdgcn_perm(__float_as_uint(b), __float_as_uint(a), 0x07060302u);
        const float r0 = a - __uint_as_float(hw << 16);
        const float r1 = b - __uint_as_float(hw & 0xffff0000u);
        const unsigned mw = __builtin_amdgcn_perm(__float_as_uint(r1), __float_as_uint(r0), 0x07060302u);
        const float s0 = r0 - __uint_as_float(mw << 16);
        const float s1 = r1 - __uint_as_float(mw & 0xffff0000u);
        const unsigned lw = __builtin_amdgcn_perm(__float_as_uint(s1), __float_as_uint(s0), 0x07060302u);
        hp[p] = hw; mp[p] = mw; lp[p] = lw;
    }
}

// ---------------- Prep: w -> frag-ordered bf16 split arrays ----------------
// Array layout (contiguous): [term h/m/l][kb][nt][lane], elem = short8
__global__ __launch_bounds__(256)
void prep_w(const float* __restrict__ w, short8* __restrict__ Bh,
            short8* __restrict__ Bm, short8* __restrict__ Bl) {
    const int t = blockIdx.x * 256 + threadIdx.x;   // [0, NF)
    const int lane = t & 63;
    const int nt = (t >> 6) & 3;
    const int kb = t >> 8;
    const int e = nt * 16 + (lane & 15);
    const int k = kb * 32 + (lane >> 4) * 8;

    const float* src = w + (size_t)e * D_TOTAL + k;
    float v[8];
    *reinterpret_cast<float4*>(&v[0]) = *reinterpret_cast<const float4*>(src);
    *reinterpret_cast<float4*>(&v[4]) = *reinterpret_cast<const float4*>(src + 4);

    short8 h, m, l;
    split3(v, h, m, l);
    Bh[t] = h; Bm[t] = m; Bl[t] = l;
}

#define LOADX(DST, PH) {                                                                  \
    const float* ap0 = xb + (PH) * 32;                                                    \
    *reinterpret_cast<float4*>(&(DST)[0][0]) = *reinterpret_cast<const float4*>(ap0);     \
    *reinterpret_cast<float4*>(&(DST)[0][4]) = *reinterpret_cast<const float4*>(ap0 + 4); \
    const float* ap1 = ap0 + (size_t)16 * D_TOTAL;                                        \
    *reinterpret_cast<float4*>(&(DST)[1][0]) = *reinterpret_cast<const float4*>(ap1);     \
    *reinterpret_cast<float4*>(&(DST)[1][4]) = *reinterpret_cast<const float4*>(ap1 + 4); \
}

// ---------------- GEMM: canonical 2-phase LDS-dbuf pipeline ----------------
// grid (64, 8): 128 tokens x K-chunk 512. Block = 4 waves x 32 tokens; all
// waves share the K-step. B reg-staged into LDS dbuf (T14 split); x in reg
// dbuf drained only at the barrier. B reads are lgkmcnt ds_reads (short).
__global__ __launch_bounds__(256, 2)
void gemm_pipe(const float* __restrict__ x, const short8* __restrict__ Ball,
               float* __restrict__ part) {
    __shared__ short8 Bs[2][12 * 64];   // 24 KB double buffer

    const int tid = threadIdx.x;
    const int lane = tid & 63;
    const int wv = tid >> 6;            // 0..3
    const int s = blockIdx.y;
    const int tok0 = blockIdx.x * 128 + wv * 32;
    const int kb0 = s * NPH;            // global kb base for this block

    const int row = lane & 15;
    const int kq = lane >> 4;
    const float* xb = x + (size_t)(tok0 + row) * D_TOTAL + s * KCH + kq * 8;

    // this thread stages frags f = wv*3 + i (i=0..2); term = f>>2, nt = f&3
    size_t stg_src[3];
    int stg_dst[3];
#pragma unroll
    for (int i = 0; i < 3; ++i) {
        const int f = wv * 3 + i;
        stg_src[i] = (size_t)(f >> 2) * NF + (size_t)(f & 3) * 64 + lane;
        stg_dst[i] = f * 64 + lane;
    }

    f32x4 acc[2][4];
#pragma unroll
    for (int m = 0; m < 2; ++m)
#pragma unroll
        for (int n = 0; n < 4; ++n) acc[m][n] = (f32x4){0.f, 0.f, 0.f, 0.f};

    float xA[2][8], xB[2][8];

    // ---- prologue: stage B[ph0] into Bs[0], load x[ph0] into xA ----
    {
        short8 stg[3];
#pragma unroll
        for (int i = 0; i < 3; ++i) stg[i] = Ball[stg_src[i] + (size_t)kb0 * 256];
        LOADX(xA, 0);
#pragma unroll
        for (int i = 0; i < 3; ++i) Bs[0][stg_dst[i]] = stg[i];
    }
    __syncthreads();   // drains vmcnt (x + stage) and lgkm (ds_write)

#pragma unroll
    for (int ph = 0; ph < NPH; ++ph) {
        const int cur = ph & 1;

        // 1. issue next-phase B stage loads (global -> reg, in flight all phase)
        short8 stg[3];
        if (ph < NPH - 1) {
#pragma unroll
            for (int i = 0; i < 3; ++i)
                stg[i] = Ball[stg_src[i] + (size_t)(kb0 + ph + 1) * 256];
        }

        // 2. issue next-phase x loads (reg dbuf; drained at barrier)
        if (ph < NPH - 1) {
            if (cur == 0) { LOADX(xB, ph + 1); }
            else          { LOADX(xA, ph + 1); }
        }

        // 3. ds_read the 12 B fragments of this phase (lgkmcnt, short)
        short8 bf[12];
#pragma unroll
        for (int f = 0; f < 12; ++f) bf[f] = Bs[cur][f * 64 + lane];

        // 4. split x + 48 MFMA (6 terms x 2 m x 4 nt)
#pragma unroll
        for (int m = 0; m < 2; ++m) {
            short8 ah, am_, al;
            split3v(cur == 0 ? xA[m] : xB[m], ah, am_, al);
#pragma unroll
            for (int nt = 0; nt < 4; ++nt) acc[m][nt] = __builtin_amdgcn_mfma_f32_16x16x32_bf16(ah,  bf[nt],     acc[m][nt], 0, 0, 0);
#pragma unroll
            for (int nt = 0; nt < 4; ++nt) acc[m][nt] = __builtin_amdgcn_mfma_f32_16x16x32_bf16(ah,  bf[4 + nt], acc[m][nt], 0, 0, 0);
#pragma unroll
            for (int nt = 0; nt < 4; ++nt) acc[m][nt] = __builtin_amdgcn_mfma_f32_16x16x32_bf16(am_, bf[nt],     acc[m][nt], 0, 0, 0);
#pragma unroll
            for (int nt = 0; nt < 4; ++nt) acc[m][nt] = __builtin_amdgcn_mfma_f32_16x16x32_bf16(am_, bf[4 + nt], acc[m][nt], 0, 0, 0);
#pragma unroll
            for (int nt = 0; nt < 4; ++nt) acc[m][nt] = __builtin_amdgcn_mfma_f32_16x16x32_bf16(ah,  bf[8 + nt], acc[m][nt], 0, 0, 0);
#pragma unroll
            for (int nt = 0; nt < 4; ++nt) acc[m][nt] = __builtin_amdgcn_mfma_f32_16x16x32_bf16(al,  bf[nt],     acc[m][nt], 0, 0, 0);
        }

        // 5. write staged B to the other buffer (compiler waits vmcnt for stg here)
        if (ph < NPH - 1) {
#pragma unroll
            for (int i = 0; i < 3; ++i) Bs[cur ^ 1][stg_dst[i]] = stg[i];
        }

        // 6. one barrier per phase
        __syncthreads();
    }

    // ---- epilogue: write partials part[s][tok][e] (verified mapping, R3/R8) ----
    float* pb = part + ((size_t)s * T_TOTAL + tok0) * E;
#pragma unroll
    for (int m = 0; m < 2; ++m) {
#pragma unroll
        for (int nt = 0; nt < 4; ++nt) {
            const int e = nt * 16 + (lane & 15);
#pragma unroll
            for (int r = 0; r < 4; ++r) {
                const int t = m * 16 + (lane >> 4) * 4 + r;
                pb[(size_t)t * E + e] = acc[m][nt][r];
            }
        }
    }
}

// ---------------- sum partials + sigmoid + top-8 (verified in R8) ----------------
__global__ __launch_bounds__(256)
void topk_kernel(const float* __restrict__ part, float* __restrict__ out) {
    __shared__ float fin[32 * 64];

    const int tid = threadIdx.x;
    const int tok0 = blockIdx.x * 32;
    const size_t base = (size_t)tok0 * E;

    const int f = tid * 8;
    float4 v0 = make_float4(0.f, 0.f, 0.f, 0.f);
    float4 v1 = make_float4(0.f, 0.f, 0.f, 0.f);
#pragma unroll
    for (int s = 0; s < S_SPLIT; ++s) {
        const float4* p = reinterpret_cast<const float4*>(
            part + (size_t)s * T_TOTAL * E + base + f);
        const float4 a = p[0];
        const float4 b = p[1];
        v0.x += a.x; v0.y += a.y; v0.z += a.z; v0.w += a.w;
        v1.x += b.x; v1.y += b.y; v1.z += b.z; v1.w += b.w;
    }
    *reinterpret_cast<float4*>(&fin[f]) = v0;
    *reinterpret_cast<float4*>(&fin[f + 4]) = v1;
    __syncthreads();

    const int lane = tid & 63;
    const int wv = tid >> 6;
#pragma unroll
    for (int rep = 0; rep < 8; ++rep) {
        const int t = wv * 8 + rep;
        float v = fin[t * 64 + lane];
        float wj[TOPK];
        int   ij[TOPK];
        float wsum = 0.f;
#pragma unroll
        for (int j = 0; j < TOPK; ++j) {
            float mx = v;
#pragma unroll
            for (int off = 32; off >= 1; off >>= 1)
                mx = fmaxf(mx, __shfl_xor(mx, off));
            const unsigned long long msk = __ballot(v == mx);
            const int widx = (int)__builtin_ctzll(msk);   // lowest index on ties (stable)
            wj[j] = 1.f / (1.f + expf(-mx));
            ij[j] = widx;
            wsum += wj[j];
            if (lane == widx) v = -INFINITY;
        }
        const float inv = 1.f / fmaxf(wsum, 1e-12f);
        const int tg = tok0 + t;
        if (lane == 0) {
#pragma unroll
            for (int j = 0; j < TOPK; ++j)
                out[(size_t)tg * TOPK + j] = wj[j] * inv;
#pragma unroll
            for (int j = 0; j < TOPK; ++j)
                out[(size_t)T_TOTAL * TOPK + (size_t)tg * TOPK + j] = (float)ij[j];
        }
    }
}

extern "C" void kernel_launch(void* const* d_in, const int* in_sizes, int n_in,
                              void* d_out, int out_size, void* d_ws, size_t ws_size,
                              hipStream_t stream) {
    const float* x = (const float*)d_in[0];
    const float* w = (const float*)d_in[1];
    float* out = (float*)d_out;

    float* part = (float*)d_ws;   // 8 * 8192 * 64 * 4 = 16 MB
    short8* Bh = (short8*)((char*)d_ws + (size_t)S_SPLIT * T_TOTAL * E * sizeof(float));
    short8* Bm = Bh + (size_t)NF;
    short8* Bl = Bm + (size_t)NF;

    prep_w<<<NF / 256, 256, 0, stream>>>(w, Bh, Bm, Bl);
    dim3 g(T_TOTAL / 128, S_SPLIT);
    gemm_pipe<<<g, 256, 0, stream>>>(x, Bh, part);
    topk_kernel<<<T_TOTAL / 32, 256, 0, stream>>>(part, out);
}